// Round 2
// 245.750 us; speedup vs baseline: 1.0704x; 1.0704x over previous
//
#include <hip/hip_runtime.h>
#include <math.h>

#define H 4096
#define INP 512
#define OUTN 64
#define H4 (H / 4)                    // 1024 float4 per row
#define SPLITS 512
#define RPS (H / SPLITS)              // 8 rows per split

// Native clang vector: accepted by __builtin_nontemporal_{load,store}
// (HIP's float4 is a class and is rejected).
typedef float fx4 __attribute__((ext_vector_type(4)));

// ---------------------------------------------------------------------------
// K1: partial[s][j] = sum_{i in split s} hidden[i] * (w[i,j] + plas[i,j]*hebb[i,j])
// grid (H4/256=4, SPLITS=512) = 2048 blocks, 8192 waves -> full occupancy target.
// Grouped 6-load bodies (2 rows x 3 streams), fully unrolled: deep load pipeline.
// w/plas are pure streams (no reuse) -> nontemporal, keeping hebb L3-resident
// for K3's re-read.
// ---------------------------------------------------------------------------
__global__ __launch_bounds__(256) void k_partial(
    const float* __restrict__ hidden,
    const float* __restrict__ w,
    const float* __restrict__ plas,
    const float* __restrict__ hebb,
    float* __restrict__ partial)
{
    const int col4 = blockIdx.x * 256 + threadIdx.x;   // 0..1023
    const int i0   = blockIdx.y * RPS;
    const fx4* __restrict__ w4 = (const fx4*)w;
    const fx4* __restrict__ p4 = (const fx4*)plas;
    const fx4* __restrict__ h4 = (const fx4*)hebb;

    fx4 acc = (fx4)(0.f);
    size_t idx = (size_t)i0 * H4 + col4;
#pragma unroll
    for (int r = 0; r < RPS; r += 2) {
        const float hv0 = hidden[i0 + r];          // wave-uniform -> scalar-cached
        const float hv1 = hidden[i0 + r + 1];
        const fx4 wv0 = __builtin_nontemporal_load(w4 + idx);
        const fx4 pv0 = __builtin_nontemporal_load(p4 + idx);
        const fx4 hb0 = h4[idx];
        const fx4 wv1 = __builtin_nontemporal_load(w4 + idx + H4);
        const fx4 pv1 = __builtin_nontemporal_load(p4 + idx + H4);
        const fx4 hb1 = h4[idx + H4];
        acc += hv0 * (wv0 + pv0 * hb0) + hv1 * (wv1 + pv1 * hb1);
        idx += 2 * (size_t)H4;
    }
    ((fx4*)partial)[(size_t)blockIdx.y * H4 + col4] = acc;
}

// ---------------------------------------------------------------------------
// K2: x[j] = relu( sum_s partial[s][j] + W_i2h[j,:]@inp + b[j] )
// Lanes run along j -> partial reads fully coalesced. 256 threads =
// 8 s-groups x 32 columns; grid = H/32 = 128 blocks.
// ---------------------------------------------------------------------------
__global__ __launch_bounds__(256) void k_reduce_x(
    const float* __restrict__ partial,
    const float* __restrict__ inp,
    const float* __restrict__ W_i2h,
    const float* __restrict__ b_i2h,
    float* __restrict__ x_out)
{
    const int jl  = threadIdx.x & 31;
    const int grp = threadIdx.x >> 5;          // 0..7
    const int j   = blockIdx.x * 32 + jl;

    // split-K reduction: group grp owns s in [grp*64, grp*64+64)
    float sum = 0.f;
    const float* __restrict__ p = partial + (size_t)grp * 64 * H + j;
#pragma unroll 8
    for (int s = 0; s < 64; ++s)
        sum += p[(size_t)s * H];

    // i2h partial dot: group grp owns float4 k-range [grp*16, grp*16+16)
    const fx4* __restrict__ row4 = (const fx4*)(W_i2h + (size_t)j * INP);
    const fx4* __restrict__ in4  = (const fx4*)inp;
#pragma unroll
    for (int c = 0; c < 16; ++c) {
        const fx4 a = row4[grp * 16 + c];
        const fx4 b = in4[grp * 16 + c];
        sum += a.x * b.x + a.y * b.y + a.z * b.z + a.w * b.w;
    }

    __shared__ float red[8][32];
    red[grp][jl] = sum;
    __syncthreads();
    if (threadIdx.x < 32) {
        float t = 0.f;
#pragma unroll
        for (int g = 0; g < 8; ++g) t += red[g][jl];
        const float pre = t + b_i2h[j];
        x_out[j] = pre > 0.f ? pre : 0.f;
    }
}

// ---------------------------------------------------------------------------
// K3: hebb_new[i,j] = (1-learn)*hebb[i,j] + learn*hidden[i]*x[j]
// One block per row; all 8 loads hoisted for ILP; nontemporal stores (write-only).
// hebb read should be largely L3-hit (K1 NT-protected it).
// ---------------------------------------------------------------------------
__global__ __launch_bounds__(256) void k_hebb(
    const float* __restrict__ hebb,
    const float* __restrict__ hidden,
    const float* __restrict__ x,
    const float* __restrict__ learn,
    float* __restrict__ hebb_out)
{
    const int i = blockIdx.x;
    const float lr   = learn[0];
    const float om   = 1.f - lr;
    const float coef = lr * hidden[i];
    const fx4* __restrict__ hb4 = (const fx4*)hebb + (size_t)i * H4;
    const fx4* __restrict__ xx4 = (const fx4*)x;
    fx4* __restrict__ o4 = (fx4*)hebb_out + (size_t)i * H4;

    const int t = threadIdx.x;
    const fx4 a0 = hb4[t];
    const fx4 a1 = hb4[t + 256];
    const fx4 a2 = hb4[t + 512];
    const fx4 a3 = hb4[t + 768];
    const fx4 x0 = xx4[t];
    const fx4 x1 = xx4[t + 256];
    const fx4 x2 = xx4[t + 512];
    const fx4 x3 = xx4[t + 768];
    __builtin_nontemporal_store(om * a0 + coef * x0, o4 + t);
    __builtin_nontemporal_store(om * a1 + coef * x1, o4 + t + 256);
    __builtin_nontemporal_store(om * a2 + coef * x2, o4 + t + 512);
    __builtin_nontemporal_store(om * a3 + coef * x3, o4 + t + 768);
}

// ---------------------------------------------------------------------------
// K4: out[o] = tanh(x @ W_h2o[o,:] + b_h2o[o]); one block per o
// ---------------------------------------------------------------------------
__global__ __launch_bounds__(256) void k_out(
    const float* __restrict__ x,
    const float* __restrict__ W_h2o,
    const float* __restrict__ b_h2o,
    float* __restrict__ out)
{
    const int o = blockIdx.x;
    const fx4* __restrict__ row4 = (const fx4*)(W_h2o + (size_t)o * H);
    const fx4* __restrict__ x4   = (const fx4*)x;
    float sum = 0.f;
#pragma unroll
    for (int c = threadIdx.x; c < H4; c += 256) {
        const fx4 a = row4[c];
        const fx4 b = x4[c];
        sum += a.x * b.x + a.y * b.y + a.z * b.z + a.w * b.w;
    }
#pragma unroll
    for (int off = 32; off > 0; off >>= 1)
        sum += __shfl_down(sum, off, 64);
    __shared__ float red[4];
    const int lane = threadIdx.x & 63;
    const int wave = threadIdx.x >> 6;
    if (lane == 0) red[wave] = sum;
    __syncthreads();
    if (threadIdx.x == 0) {
        const float s = red[0] + red[1] + red[2] + red[3];
        out[o] = tanhf(s + b_h2o[o]);
    }
}

extern "C" void kernel_launch(void* const* d_in, const int* in_sizes, int n_in,
                              void* d_out, int out_size, void* d_ws, size_t ws_size,
                              hipStream_t stream)
{
    const float* inp    = (const float*)d_in[0];
    const float* hidden = (const float*)d_in[1];
    const float* hebb   = (const float*)d_in[2];
    const float* W_i2h  = (const float*)d_in[3];
    const float* b_i2h  = (const float*)d_in[4];
    const float* w      = (const float*)d_in[5];
    const float* plas   = (const float*)d_in[6];
    const float* learn  = (const float*)d_in[7];
    const float* W_h2o  = (const float*)d_in[8];
    const float* b_h2o  = (const float*)d_in[9];

    float* out      = (float*)d_out;        // [64]
    float* x        = out + OUTN;           // [4096]
    float* hebb_out = x + H;                // [4096*4096]

    // Scratch for split-K partials: 512*4096 floats = 8 MB.
    // Prefer d_ws; else borrow the (not-yet-written) hebb output region —
    // stream order guarantees k_reduce_x consumes it before k_hebb overwrites.
    const size_t part_bytes = (size_t)SPLITS * H * sizeof(float);
    float* partial = (ws_size >= part_bytes) ? (float*)d_ws : hebb_out;

    k_partial<<<dim3(H4 / 256, SPLITS), 256, 0, stream>>>(hidden, w, plas, hebb, partial);
    k_reduce_x<<<H / 32, 256, 0, stream>>>(partial, inp, W_i2h, b_i2h, x);
    k_hebb<<<H, 256, 0, stream>>>(hebb, hidden, x, learn, hebb_out);
    k_out<<<OUTN, 256, 0, stream>>>(x, W_h2o, b_h2o, out);
}

// Round 3
// 241.611 us; speedup vs baseline: 1.0888x; 1.0171x over previous
//
#include <hip/hip_runtime.h>
#include <math.h>

#define H 4096
#define INP 512
#define OUTN 64
#define H4 (H / 4)                    // 1024 float4 per row
#define SPLITS 512
#define RPS (H / SPLITS)              // 8 rows per split

// Native clang vector: accepted by __builtin_nontemporal_{load,store}.
typedef float fx4 __attribute__((ext_vector_type(4)));

// ---------------------------------------------------------------------------
// K1: partial[s][j] = sum_{i in split s} hidden[i] * (w[i,j] + plas[i,j]*hebb[i,j])
// grid (4, 512) = 2048 blocks. ALL 24 float4 loads staged into register arrays
// BEFORE any FMA: forces ~110 VGPR and 24 outstanding loads per wave so the
// kernel is pipeline-deep instead of latency-bound (R2: VGPR=36 -> only ~2-3
// loads in flight, VALUBusy 2%, 4 TB/s effective).
// hebb uses regular loads (keep L3-resident for k_tail's re-read);
// w/plas are single-use streams -> nontemporal.
// ---------------------------------------------------------------------------
__global__ __launch_bounds__(256) void k_partial(
    const float* __restrict__ hidden,
    const float* __restrict__ w,
    const float* __restrict__ plas,
    const float* __restrict__ hebb,
    float* __restrict__ partial)
{
    const int col4 = blockIdx.x * 256 + threadIdx.x;   // 0..1023
    const int i0   = blockIdx.y * RPS;
    const fx4* __restrict__ w4 = (const fx4*)w;
    const fx4* __restrict__ p4 = (const fx4*)plas;
    const fx4* __restrict__ h4 = (const fx4*)hebb;
    const size_t base = (size_t)i0 * H4 + col4;

    fx4 hb[RPS], wv[RPS], pv[RPS];
#pragma unroll
    for (int r = 0; r < RPS; ++r)
        hb[r] = h4[base + (size_t)r * H4];
#pragma unroll
    for (int r = 0; r < RPS; ++r)
        wv[r] = __builtin_nontemporal_load(w4 + base + (size_t)r * H4);
#pragma unroll
    for (int r = 0; r < RPS; ++r)
        pv[r] = __builtin_nontemporal_load(p4 + base + (size_t)r * H4);

    fx4 acc = (fx4)(0.f);
#pragma unroll
    for (int r = 0; r < RPS; ++r)
        acc += hidden[i0 + r] * (wv[r] + pv[r] * hb[r]);

    ((fx4*)partial)[(size_t)blockIdx.y * H4 + col4] = acc;
}

// ---------------------------------------------------------------------------
// K2: x[j] = relu( sum_s partial[s][j] + W_i2h[j,:]@inp + b[j] )
// 1024-thread blocks: 32 s-groups x 32 j-columns -> 4x the waves of R2's
// version (was 512 waves chip-wide doing 16KB-strided latency-bound reads).
// grid = H/32 = 128 blocks.
// ---------------------------------------------------------------------------
__global__ __launch_bounds__(1024) void k_reduce_x(
    const float* __restrict__ partial,
    const float* __restrict__ inp,
    const float* __restrict__ W_i2h,
    const float* __restrict__ b_i2h,
    float* __restrict__ x_out)
{
    const int jl  = threadIdx.x & 31;
    const int grp = threadIdx.x >> 5;          // 0..31
    const int j   = blockIdx.x * 32 + jl;

    // split-K reduction: group grp owns s in [grp*16, grp*16+16)
    float sum = 0.f;
    const float* __restrict__ p = partial + (size_t)grp * (SPLITS / 32) * H + j;
#pragma unroll
    for (int s = 0; s < SPLITS / 32; ++s)      // 16
        sum += p[(size_t)s * H];

    // i2h partial dot: group grp owns float4 k-range [grp*4, grp*4+4)
    const fx4* __restrict__ row4 = (const fx4*)(W_i2h + (size_t)j * INP);
    const fx4* __restrict__ in4  = (const fx4*)inp;
#pragma unroll
    for (int c = 0; c < 4; ++c) {
        const fx4 a = row4[grp * 4 + c];
        const fx4 b = in4[grp * 4 + c];
        sum += a.x * b.x + a.y * b.y + a.z * b.z + a.w * b.w;
    }

    __shared__ float red[32][33];              // +1 pad: conflict-free column read
    red[grp][jl] = sum;
    __syncthreads();
    if (threadIdx.x < 32) {
        float t = 0.f;
#pragma unroll
        for (int g = 0; g < 32; ++g) t += red[g][jl];
        const float pre = t + b_i2h[j];
        x_out[j] = pre > 0.f ? pre : 0.f;
    }
}

// ---------------------------------------------------------------------------
// K3 (fused tail): blocks [0,H) do the hebb row update; blocks [H, H+OUTN)
// compute out[o] = tanh(x @ W_h2o[o,:] + b). One launch instead of two.
// hebb read: NT (single use here, should be L3-hit from K1's regular load);
// hebb_out: NT store (write-only stream).
// ---------------------------------------------------------------------------
__global__ __launch_bounds__(256) void k_tail(
    const float* __restrict__ hebb,
    const float* __restrict__ hidden,
    const float* __restrict__ x,
    const float* __restrict__ learn,
    const float* __restrict__ W_h2o,
    const float* __restrict__ b_h2o,
    float* __restrict__ hebb_out,
    float* __restrict__ out)
{
    if (blockIdx.x < H) {
        const int i = blockIdx.x;
        const float lr   = learn[0];
        const float om   = 1.f - lr;
        const float coef = lr * hidden[i];
        const fx4* __restrict__ hb4 = (const fx4*)hebb + (size_t)i * H4;
        const fx4* __restrict__ xx4 = (const fx4*)x;
        fx4* __restrict__ o4 = (fx4*)hebb_out + (size_t)i * H4;

        const int t = threadIdx.x;
        const fx4 a0 = __builtin_nontemporal_load(hb4 + t);
        const fx4 a1 = __builtin_nontemporal_load(hb4 + t + 256);
        const fx4 a2 = __builtin_nontemporal_load(hb4 + t + 512);
        const fx4 a3 = __builtin_nontemporal_load(hb4 + t + 768);
        const fx4 x0 = xx4[t];
        const fx4 x1 = xx4[t + 256];
        const fx4 x2 = xx4[t + 512];
        const fx4 x3 = xx4[t + 768];
        __builtin_nontemporal_store(om * a0 + coef * x0, o4 + t);
        __builtin_nontemporal_store(om * a1 + coef * x1, o4 + t + 256);
        __builtin_nontemporal_store(om * a2 + coef * x2, o4 + t + 512);
        __builtin_nontemporal_store(om * a3 + coef * x3, o4 + t + 768);
    } else {
        const int o = blockIdx.x - H;          // 0..63
        const fx4* __restrict__ row4 = (const fx4*)(W_h2o + (size_t)o * H);
        const fx4* __restrict__ x4   = (const fx4*)x;
        float sum = 0.f;
#pragma unroll
        for (int c = threadIdx.x; c < H4; c += 256) {
            const fx4 a = row4[c];
            const fx4 b = x4[c];
            sum += a.x * b.x + a.y * b.y + a.z * b.z + a.w * b.w;
        }
#pragma unroll
        for (int off = 32; off > 0; off >>= 1)
            sum += __shfl_down(sum, off, 64);
        __shared__ float red[4];
        const int lane = threadIdx.x & 63;
        const int wave = threadIdx.x >> 6;
        if (lane == 0) red[wave] = sum;
        __syncthreads();
        if (threadIdx.x == 0) {
            const float s = red[0] + red[1] + red[2] + red[3];
            out[o] = tanhf(s + b_h2o[o]);
        }
    }
}

extern "C" void kernel_launch(void* const* d_in, const int* in_sizes, int n_in,
                              void* d_out, int out_size, void* d_ws, size_t ws_size,
                              hipStream_t stream)
{
    const float* inp    = (const float*)d_in[0];
    const float* hidden = (const float*)d_in[1];
    const float* hebb   = (const float*)d_in[2];
    const float* W_i2h  = (const float*)d_in[3];
    const float* b_i2h  = (const float*)d_in[4];
    const float* w      = (const float*)d_in[5];
    const float* plas   = (const float*)d_in[6];
    const float* learn  = (const float*)d_in[7];
    const float* W_h2o  = (const float*)d_in[8];
    const float* b_h2o  = (const float*)d_in[9];

    float* out      = (float*)d_out;        // [64]
    float* x        = out + OUTN;           // [4096]
    float* hebb_out = x + H;                // [4096*4096]

    // Scratch for split-K partials: 512*4096 floats = 8 MB.
    // Prefer d_ws; else borrow the (not-yet-written) hebb output region —
    // stream order guarantees k_reduce_x consumes it before k_tail overwrites.
    const size_t part_bytes = (size_t)SPLITS * H * sizeof(float);
    float* partial = (ws_size >= part_bytes) ? (float*)d_ws : hebb_out;

    k_partial<<<dim3(H4 / 256, SPLITS), 256, 0, stream>>>(hidden, w, plas, hebb, partial);
    k_reduce_x<<<H / 32, 1024, 0, stream>>>(partial, inp, W_i2h, b_i2h, x);
    k_tail<<<H + OUTN, 256, 0, stream>>>(hebb, hidden, x, learn, W_h2o, b_h2o, hebb_out, out);
}

// Round 4
// 239.582 us; speedup vs baseline: 1.0980x; 1.0085x over previous
//
#include <hip/hip_runtime.h>
#include <math.h>

#define H 4096
#define INP 512
#define OUTN 64
#define H4 (H / 4)                    // 1024 float4 per row
#define SPLITS 512
#define RPS (H / SPLITS)              // 8 rows per split

// Native clang vector: accepted by __builtin_nontemporal_{load,store}.
typedef float fx4 __attribute__((ext_vector_type(4)));

// ---------------------------------------------------------------------------
// K1: partial[s][j] = sum_{i in split s} hidden[i] * (w[i,j] + plas[i,j]*hebb[i,j])
// grid (4, 512) = 2048 blocks.
// R3 lesson: register-staging alone is UNDONE by the pre-RA scheduler (VGPR
// stayed 36). This version pins the pipeline with sched_barrier(0): all 24
// float4 loads issue BEFORE any FMA -> ~96 live data VGPRs -> 24 outstanding
// loads/wave. Loads issue row-interleaved (hb,w,p) so the drain overlaps the
// FMA sequence via counted vmcnt.
// hebb uses regular loads (keep L3-resident for k_tail); w/plas single-use -> NT.
// ---------------------------------------------------------------------------
__global__ __launch_bounds__(256) void k_partial(
    const float* __restrict__ hidden,
    const float* __restrict__ w,
    const float* __restrict__ plas,
    const float* __restrict__ hebb,
    float* __restrict__ partial)
{
    const int col4 = blockIdx.x * 256 + threadIdx.x;   // 0..1023
    const int i0   = blockIdx.y * RPS;
    const fx4* __restrict__ w4 = (const fx4*)w;
    const fx4* __restrict__ p4 = (const fx4*)plas;
    const fx4* __restrict__ h4 = (const fx4*)hebb;
    const size_t base = (size_t)i0 * H4 + col4;

    float hv[RPS];
#pragma unroll
    for (int r = 0; r < RPS; ++r)
        hv[r] = hidden[i0 + r];                        // wave-uniform -> SGPR

    fx4 hb[RPS], wv[RPS], pv[RPS];
#pragma unroll
    for (int r = 0; r < RPS; ++r) {
        const size_t idx = base + (size_t)r * H4;
        hb[r] = h4[idx];
        wv[r] = __builtin_nontemporal_load(w4 + idx);
        pv[r] = __builtin_nontemporal_load(p4 + idx);
    }
    __builtin_amdgcn_sched_barrier(0);   // fence: no FMA hoists above, no load sinks below

    fx4 acc = (fx4)(0.f);
#pragma unroll
    for (int r = 0; r < RPS; ++r)
        acc += hv[r] * (wv[r] + pv[r] * hb[r]);

    ((fx4*)partial)[(size_t)blockIdx.y * H4 + col4] = acc;
}

// ---------------------------------------------------------------------------
// K2: x[j] = relu( sum_s partial[s][j] + W_i2h[j,:]@inp + b[j] )
// 1024-thread blocks: 32 s-groups x 32 j-columns; grid = H/32 = 128 blocks.
// ---------------------------------------------------------------------------
__global__ __launch_bounds__(1024) void k_reduce_x(
    const float* __restrict__ partial,
    const float* __restrict__ inp,
    const float* __restrict__ W_i2h,
    const float* __restrict__ b_i2h,
    float* __restrict__ x_out)
{
    const int jl  = threadIdx.x & 31;
    const int grp = threadIdx.x >> 5;          // 0..31
    const int j   = blockIdx.x * 32 + jl;

    // split-K reduction: group grp owns s in [grp*16, grp*16+16)
    float ps[SPLITS / 32];
    const float* __restrict__ p = partial + (size_t)grp * (SPLITS / 32) * H + j;
#pragma unroll
    for (int s = 0; s < SPLITS / 32; ++s)
        ps[s] = p[(size_t)s * H];
    __builtin_amdgcn_sched_barrier(0);

    float sum = 0.f;
#pragma unroll
    for (int s = 0; s < SPLITS / 32; ++s)
        sum += ps[s];

    // i2h partial dot: group grp owns float4 k-range [grp*4, grp*4+4)
    const fx4* __restrict__ row4 = (const fx4*)(W_i2h + (size_t)j * INP);
    const fx4* __restrict__ in4  = (const fx4*)inp;
#pragma unroll
    for (int c = 0; c < 4; ++c) {
        const fx4 a = row4[grp * 4 + c];
        const fx4 b = in4[grp * 4 + c];
        sum += a.x * b.x + a.y * b.y + a.z * b.z + a.w * b.w;
    }

    __shared__ float red[32][33];              // +1 pad: conflict-free column read
    red[grp][jl] = sum;
    __syncthreads();
    if (threadIdx.x < 32) {
        float t = 0.f;
#pragma unroll
        for (int g = 0; g < 32; ++g) t += red[g][jl];
        const float pre = t + b_i2h[j];
        x_out[j] = pre > 0.f ? pre : 0.f;
    }
}

// ---------------------------------------------------------------------------
// K3 (fused tail): blocks [0,H) do the hebb row update; blocks [H, H+OUTN)
// compute out[o] = tanh(x @ W_h2o[o,:] + b).
// R2 error fixed: hebb loads are REGULAR (NT was bypassing the L3 residency
// k_partial established). Same sched_barrier load-pipeline fence as K1.
// hebb_out: NT store (write-only stream, don't pollute caches).
// ---------------------------------------------------------------------------
__global__ __launch_bounds__(256) void k_tail(
    const float* __restrict__ hebb,
    const float* __restrict__ hidden,
    const float* __restrict__ x,
    const float* __restrict__ learn,
    const float* __restrict__ W_h2o,
    const float* __restrict__ b_h2o,
    float* __restrict__ hebb_out,
    float* __restrict__ out)
{
    if (blockIdx.x < H) {
        const int i = blockIdx.x;
        const float lr   = learn[0];
        const float om   = 1.f - lr;
        const float coef = lr * hidden[i];
        const fx4* __restrict__ hb4 = (const fx4*)hebb + (size_t)i * H4;
        const fx4* __restrict__ xx4 = (const fx4*)x;
        fx4* __restrict__ o4 = (fx4*)hebb_out + (size_t)i * H4;

        const int t = threadIdx.x;
        fx4 a[4], xv[4];
#pragma unroll
        for (int q = 0; q < 4; ++q) {
            a[q]  = hb4[t + q * 256];
            xv[q] = xx4[t + q * 256];
        }
        __builtin_amdgcn_sched_barrier(0);
#pragma unroll
        for (int q = 0; q < 4; ++q)
            __builtin_nontemporal_store(om * a[q] + coef * xv[q], o4 + t + q * 256);
    } else {
        const int o = blockIdx.x - H;          // 0..63
        const fx4* __restrict__ row4 = (const fx4*)(W_h2o + (size_t)o * H);
        const fx4* __restrict__ x4   = (const fx4*)x;
        float sum = 0.f;
#pragma unroll
        for (int c = threadIdx.x; c < H4; c += 256) {
            const fx4 a = row4[c];
            const fx4 b = x4[c];
            sum += a.x * b.x + a.y * b.y + a.z * b.z + a.w * b.w;
        }
#pragma unroll
        for (int off = 32; off > 0; off >>= 1)
            sum += __shfl_down(sum, off, 64);
        __shared__ float red[4];
        const int lane = threadIdx.x & 63;
        const int wave = threadIdx.x >> 6;
        if (lane == 0) red[wave] = sum;
        __syncthreads();
        if (threadIdx.x == 0) {
            const float s = red[0] + red[1] + red[2] + red[3];
            out[o] = tanhf(s + b_h2o[o]);
        }
    }
}

extern "C" void kernel_launch(void* const* d_in, const int* in_sizes, int n_in,
                              void* d_out, int out_size, void* d_ws, size_t ws_size,
                              hipStream_t stream)
{
    const float* inp    = (const float*)d_in[0];
    const float* hidden = (const float*)d_in[1];
    const float* hebb   = (const float*)d_in[2];
    const float* W_i2h  = (const float*)d_in[3];
    const float* b_i2h  = (const float*)d_in[4];
    const float* w      = (const float*)d_in[5];
    const float* plas   = (const float*)d_in[6];
    const float* learn  = (const float*)d_in[7];
    const float* W_h2o  = (const float*)d_in[8];
    const float* b_h2o  = (const float*)d_in[9];

    float* out      = (float*)d_out;        // [64]
    float* x        = out + OUTN;           // [4096]
    float* hebb_out = x + H;                // [4096*4096]

    // Scratch for split-K partials: 512*4096 floats = 8 MB.
    // Prefer d_ws; else borrow the (not-yet-written) hebb output region —
    // stream order guarantees k_reduce_x consumes it before k_tail overwrites.
    const size_t part_bytes = (size_t)SPLITS * H * sizeof(float);
    float* partial = (ws_size >= part_bytes) ? (float*)d_ws : hebb_out;

    k_partial<<<dim3(H4 / 256, SPLITS), 256, 0, stream>>>(hidden, w, plas, hebb, partial);
    k_reduce_x<<<H / 32, 1024, 0, stream>>>(partial, inp, W_i2h, b_i2h, x);
    k_tail<<<H + OUTN, 256, 0, stream>>>(hebb, hidden, x, learn, W_h2o, b_h2o, hebb_out, out);
}